// Round 6
// baseline (443.109 us; speedup 1.0000x reference)
//
#include <hip/hip_runtime.h>
#include <hip/hip_bf16.h>

typedef __bf16 bf16x8 __attribute__((ext_vector_type(8)));
typedef float f32x4 __attribute__((ext_vector_type(4)));

#define DEVI static __device__ __forceinline__

DEVI void load_lds16(const void* g, void* l) {
  __builtin_amdgcn_global_load_lds(
      (const __attribute__((address_space(1))) void*)g,
      (__attribute__((address_space(3))) void*)l, 16, 0, 0);
}

DEVI unsigned short f2b(float f) { return __bfloat16_as_ushort(__float2bfloat16(f)); }
DEVI float b2f(unsigned short u) {
  union { unsigned int i; float f; } c;
  c.i = ((unsigned int)u) << 16;
  return c.f;
}
DEVI float sigm(float x) { return 1.0f / (1.0f + __expf(-x)); }
DEVI float tanh_fast(float x) { return 2.0f / (1.0f + __expf(-2.0f * x)) - 1.0f; }

// involutive 16B-granule swizzle: XOR byte-bits 4-6 with bits 7-9 (verified 0-conflict r3/r4).
DEVI int swz(int L) { return L ^ (((L >> 7) & 7) << 4); }

// ---------------------------------------------------------------- cast fp32->bf16 (identity rows)
__global__ __launch_bounds__(256) void cast_kernel(const float* __restrict__ src,
                                                   unsigned short* __restrict__ dst,
                                                   int n4) {
  const int i = blockIdx.x * 256 + threadIdx.x;
  if (i >= n4) return;
  const float4 v = reinterpret_cast<const float4*>(src)[i];
  ushort4 o;
  o.x = f2b(v.x); o.y = f2b(v.y); o.z = f2b(v.z); o.w = f2b(v.w);
  reinterpret_cast<ushort4*>(dst)[i] = o;
}

// cast + gate-interleave row permute: src row r = g*1024+h  ->  dst row 4h+g.
__global__ __launch_bounds__(256) void cast_perm_kernel(const float* __restrict__ src,
                                                        unsigned short* __restrict__ dst) {
  const int i = blockIdx.x * 256 + threadIdx.x;  // 0 .. 1M-1
  const int r = i >> 8;
  const int cw = i & 255;
  const float4 v = reinterpret_cast<const float4*>(src)[i];
  const int rp = ((r & 1023) << 2) + (r >> 10);  // 4h+g
  ushort4 o;
  o.x = f2b(v.x); o.y = f2b(v.y); o.z = f2b(v.z); o.w = f2b(v.w);
  *reinterpret_cast<ushort4*>(&dst[(size_t)rp * 1024 + (cw << 2)]) = o;
}

// bp[4h+g] = bW[g*1024+h] + bU[g*1024+h]
__global__ __launch_bounds__(256) void bias_prep(const float* __restrict__ bW,
                                                 const float* __restrict__ bU,
                                                 float* __restrict__ bp) {
  const int i = blockIdx.x * 256 + threadIdx.x;  // 0..4095
  const int h = i >> 2, g = i & 3;
  bp[i] = bW[g * 1024 + h] + bU[g * 1024 + h];
}

// ---------------------------------------------------------------- GEMM 128x256 (+ fused gates)
// C[4096,4096] = A[4096,1024] * Bm[4096,1024]^T (bf16 in, fp32 acc)
// 256 threads, 4 waves, per-wave 128x64 (wave = N quarter). Grid 512 = 2 blocks/CU
// (cross-block wave overlap hides barrier/read stalls, m114). K phased in 32-elem
// steps; 3 LDS slots x 24KB (A 8KB | B 16KB) rotation; stage(p+2) -> slot freed at
// previous barrier; counted vmcnt(6), tail vmcnt(0) (verified ledger pattern r3/r4).
template <bool FUSED, bool LAST>
__global__ __launch_bounds__(256, 2) void gemm256(
    const unsigned short* __restrict__ A,
    const unsigned short* __restrict__ Bm,
    unsigned short* __restrict__ Cout,         // used if !FUSED
    const unsigned short* __restrict__ xproj,  // used if FUSED (permuted cols)
    const float* __restrict__ bp,              // [4H] permuted combined bias
    float* __restrict__ ct,                    // [B,H] fp32 state (rw)
    unsigned short* __restrict__ htout,        // [B,H] bf16 next-step input
    float* __restrict__ out) {                 // d_out when LAST
  constexpr int K = 1024, N = 4096;
  constexpr int NPH = K / 32;   // 32 phases
  constexpr int SLOT = 24576;   // A [0,8192) = 128r x 64B ; B [8192,24576) = 256r x 64B
  __shared__ unsigned char lds[3 * SLOT];  // 72KB -> 2 blocks/CU; epilogue reuses it

  const int tid = threadIdx.x;
  const int lane = tid & 63;
  const int wc = tid >> 6;  // 0..3 : N quarter (64 cols)

  // XCD-aware block swizzle (nwg=512, divisible by 8)
  const int bid = blockIdx.x;
  const int sw = (bid & 7) * 64 + (bid >> 3);
  const int brow = (sw >> 4) * 128;
  const int bcol = (sw & 15) * 256;

  // staging geometry: 6 x 16B loads/thread/slot (A:2, B:4), swizzle on global src (rule #21)
  const int physA0 = tid * 16;
  const int physA1 = 4096 + tid * 16;
  const int LA0 = swz(physA0), LA1 = swz(physA1);
  const unsigned char* pA0 = (const unsigned char*)A + (size_t)(brow + (LA0 >> 6)) * (K * 2) + (LA0 & 63);
  const unsigned char* pA1 = (const unsigned char*)A + (size_t)(brow + (LA1 >> 6)) * (K * 2) + (LA1 & 63);
  int physB[4];
  const unsigned char* pB[4];
#pragma unroll
  for (int q = 0; q < 4; ++q) {
    physB[q] = 8192 + q * 4096 + tid * 16;
    const int LB = swz(physB[q] - 8192);
    pB[q] = (const unsigned char*)Bm + (size_t)(bcol + (LB >> 6)) * (K * 2) + (LB & 63);
  }

  // fragment read offsets (slot-relative), swizzled
  const int s16 = (lane >> 4) * 16;
  int offA[8], offB[4];
#pragma unroll
  for (int m = 0; m < 8; ++m) offA[m] = swz((m * 16 + (lane & 15)) * 64 + s16);
#pragma unroll
  for (int n = 0; n < 4; ++n) offB[n] = 8192 + swz(((wc * 64) + n * 16 + (lane & 15)) * 64 + s16);

  f32x4 acc[8][4] = {};

  auto STAGE = [&](int q) {
    unsigned char* sb = lds + (q % 3) * SLOT;
    const size_t kb = (size_t)q * 64;  // 32 K-elems = 64B per phase
    load_lds16(pA0 + kb, sb + physA0);
    load_lds16(pA1 + kb, sb + physA1);
#pragma unroll
    for (int j = 0; j < 4; ++j) load_lds16(pB[j] + kb, sb + physB[j]);
  };

  // prologue: slots 0,1 in flight (12 loads); vmcnt(6) retires slot 0's 6
  STAGE(0); STAGE(1);
  asm volatile("s_waitcnt vmcnt(6)" ::: "memory");
  __builtin_amdgcn_s_barrier();
  __builtin_amdgcn_sched_barrier(0);

  for (int p = 0; p < NPH; ++p) {
    if (p + 2 < NPH) STAGE(p + 2);  // into slot (p+2)%3 == (p-1)%3, freed at last barrier

    const unsigned char* sl = lds + (p % 3) * SLOT;
    bf16x8 af[8], bf[4];
#pragma unroll
    for (int n = 0; n < 4; ++n) bf[n] = *reinterpret_cast<const bf16x8*>(sl + offB[n]);
#pragma unroll
    for (int m = 0; m < 8; ++m) af[m] = *reinterpret_cast<const bf16x8*>(sl + offA[m]);

    __builtin_amdgcn_s_setprio(1);
#pragma unroll
    for (int m = 0; m < 8; ++m)
#pragma unroll
      for (int n = 0; n < 4; ++n)
        acc[m][n] = __builtin_amdgcn_mfma_f32_16x16x32_bf16(af[m], bf[n], acc[m][n], 0, 0, 0);
    __builtin_amdgcn_s_setprio(0);

    if (p < NPH - 1) {
      // boundary: retire slot p+1's loads (oldest 6 of 12 outstanding)
      if (p <= NPH - 3)
        asm volatile("s_waitcnt vmcnt(6)" ::: "memory");
      else
        asm volatile("s_waitcnt vmcnt(0)" ::: "memory");
      __builtin_amdgcn_s_barrier();
      __builtin_amdgcn_sched_barrier(0);
    }
  }

  // ---- epilogue: stage bf16 C tile (128x256) into LDS, padded stride 264 elems
  __syncthreads();
  unsigned short* cs = (unsigned short*)lds;
  {
    const int c0 = wc * 64 + (lane & 15);
    const int crow0 = (lane >> 4) * 4;
#pragma unroll
    for (int m = 0; m < 8; ++m)
#pragma unroll
      for (int n = 0; n < 4; ++n) {
        const int rr = m * 16 + crow0;
        const int cc = c0 + n * 16;
#pragma unroll
        for (int r = 0; r < 4; ++r) cs[(rr + r) * 264 + cc] = f2b(acc[m][n][r]);
      }
  }
  __syncthreads();

  if constexpr (!FUSED) {
    // coalesced wide stores: 128 rows x 32 granules of 16B = 4096 -> 16 iters
#pragma unroll
    for (int j = 0; j < 16; ++j) {
      const int g = tid + (j << 8);
      const int row = g >> 5, gc = g & 31;
      const uint4 v = *reinterpret_cast<const uint4*>(&cs[row * 264 + gc * 8]);
      *reinterpret_cast<uint4*>(&Cout[(size_t)(brow + row) * N + bcol + gc * 8]) = v;
    }
  } else {
    const int hbase = bcol >> 2;  // 64 h's per block
#pragma unroll 4
    for (int j = 0; j < 32; ++j) {
      const int q = tid + (j << 8);  // 0..8191 = 128 rows x 64 h
      const int row = q >> 6;
      const int hh = q & 63;
      const ushort4 pv = *reinterpret_cast<const ushort4*>(&cs[row * 264 + hh * 4]);
      const ushort4 xv = *reinterpret_cast<const ushort4*>(&xproj[(size_t)(brow + row) * N + bcol + hh * 4]);
      const float4 bpv = *reinterpret_cast<const float4*>(&bp[bcol + hh * 4]);
      const int ci = (brow + row) * 1024 + hbase + hh;
      const float c_old = ct[ci];
      const float sf = b2f(pv.x) + b2f(xv.x) + bpv.x;
      const float si = b2f(pv.y) + b2f(xv.y) + bpv.y;
      const float so = b2f(pv.z) + b2f(xv.z) + bpv.z;
      const float sg = b2f(pv.w) + b2f(xv.w) + bpv.w;
      const float f = sigm(sf);
      const float ii = sigm(si);
      const float o = sigm(so);
      const float gg = tanh_fast(sg);
      const float c = fmaf(f, c_old, ii * gg);
      const float h = o * tanh_fast(c);
      ct[ci] = c;
      if constexpr (LAST) {
        out[ci] = h;
        out[4194304 + ci] = c;
      } else {
        htout[ci] = f2b(h);
      }
    }
  }
}

// ---------------------------------------------------------------- first-step gates
__global__ __launch_bounds__(256) void gates_first(
    const unsigned short* __restrict__ xproj, const float* __restrict__ bp,
    float* __restrict__ ct, unsigned short* __restrict__ ht) {
  const int i = blockIdx.x * 256 + threadIdx.x;  // 1M threads
  const int b = i >> 8;
  const int h0 = (i & 255) << 2;
  const size_t xbase = (size_t)b * 4096 + ((size_t)h0 << 2);
  float cn[4], hn[4];
#pragma unroll
  for (int k = 0; k < 4; ++k) {
    const ushort4 pv = *reinterpret_cast<const ushort4*>(&xproj[xbase + k * 4]);
    const float4 bpv = *reinterpret_cast<const float4*>(&bp[(h0 + k) * 4]);
    const float ii = sigm(b2f(pv.y) + bpv.y);
    const float o = sigm(b2f(pv.z) + bpv.z);
    const float gg = tanh_fast(b2f(pv.w) + bpv.w);
    const float c = ii * gg;  // f*0 + i*g
    cn[k] = c;
    hn[k] = o * tanh_fast(c);
  }
  const int ci = b * 1024 + h0;
  *reinterpret_cast<float4*>(&ct[ci]) = make_float4(cn[0], cn[1], cn[2], cn[3]);
  ushort4 hb;
  hb.x = f2b(hn[0]); hb.y = f2b(hn[1]); hb.z = f2b(hn[2]); hb.w = f2b(hn[3]);
  *reinterpret_cast<ushort4*>(&ht[ci]) = hb;
}

// ---------------------------------------------------------------- launch
extern "C" void kernel_launch(void* const* d_in, const int* in_sizes, int n_in,
                              void* d_out, int out_size, void* d_ws, size_t ws_size,
                              hipStream_t stream) {
  const float* x = (const float*)d_in[0];   // [4096,1024]
  const float* W = (const float*)d_in[1];   // [4096,1024]
  const float* bW = (const float*)d_in[2];  // [4096]
  const float* U = (const float*)d_in[3];   // [4096,1024]
  const float* bU = (const float*)d_in[4];  // [4096]
  float* out = (float*)d_out;

  char* w = (char*)d_ws;
  const size_t MB = 1ull << 20;
  unsigned short* xb = (unsigned short*)(w + 0 * MB);      // 8 MB
  unsigned short* Wbp = (unsigned short*)(w + 8 * MB);     // 8 MB (gate-interleaved)
  unsigned short* Ubp = (unsigned short*)(w + 16 * MB);    // 8 MB (gate-interleaved)
  unsigned short* xproj = (unsigned short*)(w + 24 * MB);  // 32 MB [B,4H] bf16 permuted
  float* ct = (float*)(w + 56 * MB);                       // 16 MB
  unsigned short* htA = (unsigned short*)(w + 72 * MB);    // 8 MB
  unsigned short* htB = (unsigned short*)(w + 80 * MB);    // 8 MB
  float* bp = (float*)(w + 88 * MB);                       // 16 KB

  const int n4 = (4096 * 1024) / 4;
  cast_kernel<<<4096, 256, 0, stream>>>(x, xb, n4);
  cast_perm_kernel<<<4096, 256, 0, stream>>>(W, Wbp);
  cast_perm_kernel<<<4096, 256, 0, stream>>>(U, Ubp);
  bias_prep<<<16, 256, 0, stream>>>(bW, bU, bp);

  gemm256<false, false><<<512, 256, 0, stream>>>(xb, Wbp, xproj, nullptr, nullptr, nullptr, nullptr, nullptr);
  gates_first<<<4096, 256, 0, stream>>>(xproj, bp, ct, htA);

  const unsigned short* hin = htA;
  unsigned short* hout = htB;
  for (int t = 1; t <= 6; ++t) {
    gemm256<true, false><<<512, 256, 0, stream>>>(hin, Ubp, nullptr, xproj, bp, ct, hout, nullptr);
    const unsigned short* tmp = hout;
    hout = (unsigned short*)hin;
    hin = tmp;
  }
  gemm256<true, true><<<512, 256, 0, stream>>>(hin, Ubp, nullptr, xproj, bp, ct, nullptr, out);
}

// Round 7
// 402.586 us; speedup vs baseline: 1.1007x; 1.1007x over previous
//
#include <hip/hip_runtime.h>
#include <hip/hip_bf16.h>

typedef __bf16 bf16x8 __attribute__((ext_vector_type(8)));
typedef float f32x4 __attribute__((ext_vector_type(4)));

#define DEVI static __device__ __forceinline__

DEVI void load_lds16(const void* g, void* l) {
  __builtin_amdgcn_global_load_lds(
      (const __attribute__((address_space(1))) void*)g,
      (__attribute__((address_space(3))) void*)l, 16, 0, 0);
}

DEVI unsigned short f2b(float f) { return __bfloat16_as_ushort(__float2bfloat16(f)); }
DEVI float b2f(unsigned short u) {
  union { unsigned int i; float f; } c;
  c.i = ((unsigned int)u) << 16;
  return c.f;
}
DEVI float sigm(float x) { return 1.0f / (1.0f + __expf(-x)); }
DEVI float tanh_fast(float x) { return 2.0f / (1.0f + __expf(-2.0f * x)) - 1.0f; }

// involutive 16B-granule swizzle within a 32KB slot: XOR byte-bits 4-6 with bits 7-9.
DEVI int swz(int L) { return L ^ (((L >> 7) & 7) << 4); }

// ---------------------------------------------------------------- cast fp32->bf16 (identity rows)
__global__ __launch_bounds__(256) void cast_kernel(const float* __restrict__ src,
                                                   unsigned short* __restrict__ dst,
                                                   int n4) {
  const int i = blockIdx.x * 256 + threadIdx.x;
  if (i >= n4) return;
  const float4 v = reinterpret_cast<const float4*>(src)[i];
  ushort4 o;
  o.x = f2b(v.x); o.y = f2b(v.y); o.z = f2b(v.z); o.w = f2b(v.w);
  reinterpret_cast<ushort4*>(dst)[i] = o;
}

// cast + gate-interleave row permute: src row r = g*1024+h  ->  dst row 4h+g.
__global__ __launch_bounds__(256) void cast_perm_kernel(const float* __restrict__ src,
                                                        unsigned short* __restrict__ dst) {
  const int i = blockIdx.x * 256 + threadIdx.x;  // 0 .. 1M-1
  const int r = i >> 8;
  const int cw = i & 255;
  const float4 v = reinterpret_cast<const float4*>(src)[i];
  const int rp = ((r & 1023) << 2) + (r >> 10);  // 4h+g
  ushort4 o;
  o.x = f2b(v.x); o.y = f2b(v.y); o.z = f2b(v.z); o.w = f2b(v.w);
  *reinterpret_cast<ushort4*>(&dst[(size_t)rp * 1024 + (cw << 2)]) = o;
}

// bp[4h+g] = bW[g*1024+h] + bU[g*1024+h]
__global__ __launch_bounds__(256) void bias_prep(const float* __restrict__ bW,
                                                 const float* __restrict__ bU,
                                                 float* __restrict__ bp) {
  const int i = blockIdx.x * 256 + threadIdx.x;  // 0..4095
  const int h = i >> 2, g = i & 3;
  bp[i] = bW[g * 1024 + h] + bU[g * 1024 + h];
}

// ---------------------------------------------------------------- GEMM 256x256 + fused LSTM gates
// proj[4096,4096] = A[4096,1024] * Bm[4096,1024]^T (bf16 in, fp32 acc)
// K-loop: verified R4 structure (4 LDS slots x 32KB, counted vmcnt(8), XCD swizzle,
// 0 bank conflicts). Epilogue: LDS-stage bf16 tile (stride 264), then per (row,h):
//   MODE 0 FIRST: s = acc + bp;  write xpb = bf16(s); c_old = 0
//   MODE 1 MID  : s = acc + xpb; c_old = b2f(ct)
//   MODE 2 LAST : s = acc + xpb; c_old = b2f(ct); write fp32 (h, c) to out
//   c = sig(f)*c_old + sig(i)*tanh(g); h = sig(o)*tanh(c); ct=bf16(c); ht=bf16(h)
template <int MODE>
__global__ __launch_bounds__(512, 2) void gemm256(
    const unsigned short* __restrict__ A,
    const unsigned short* __restrict__ Bm,
    const unsigned short* __restrict__ xpb_r,  // MID/LAST: [B,4H] bf16 (proj+bias)
    unsigned short* __restrict__ xpb_w,        // FIRST: write
    const float* __restrict__ bp,              // FIRST: [4H] combined bias
    unsigned short* __restrict__ ct,           // [B,H] bf16 state (rw)
    unsigned short* __restrict__ htout,        // [B,H] bf16 next-step input
    float* __restrict__ out) {                 // d_out when LAST
  constexpr int K = 1024, N = 4096;
  constexpr int NPH = K / 32;  // 32 phases
  __shared__ unsigned char lds[256 * 528];  // 135168 B >= 4*32768 K-loop use

  const int tid = threadIdx.x;
  const int lane = tid & 63;
  const int wave = tid >> 6;
  const int wr = wave >> 2;  // 0..1 : M half (128 rows)
  const int wc = wave & 3;   // 0..3 : N quarter (64 cols)

  // XCD-aware block swizzle (nwg=256, divisible by 8)
  const int bid = blockIdx.x;
  const int sw = (bid & 7) * 32 + (bid >> 3);
  const int brow = (sw >> 4) * 256;
  const int bcol = (sw & 15) * 256;

  // staging geometry (swizzle via pre-permuted global source, rule #21)
  const int physA0 = tid * 16;
  const int physA1 = 8192 + tid * 16;
  const int physB0 = 16384 + tid * 16;
  const int physB1 = 24576 + tid * 16;
  const int LA0 = swz(physA0), LA1 = swz(physA1);
  const int LB0 = swz(physB0 - 16384), LB1 = swz(physB1 - 16384);
  const unsigned char* pA0 = (const unsigned char*)A + (size_t)(brow + (LA0 >> 6)) * (K * 2) + (LA0 & 63);
  const unsigned char* pA1 = (const unsigned char*)A + (size_t)(brow + (LA1 >> 6)) * (K * 2) + (LA1 & 63);
  const unsigned char* pB0 = (const unsigned char*)Bm + (size_t)(bcol + (LB0 >> 6)) * (K * 2) + (LB0 & 63);
  const unsigned char* pB1 = (const unsigned char*)Bm + (size_t)(bcol + (LB1 >> 6)) * (K * 2) + (LB1 & 63);

  // fragment read offsets (slot-relative), swizzled
  const int s16 = (lane >> 4) * 16;
  int offA[8], offB[4];
#pragma unroll
  for (int m = 0; m < 8; ++m) {
    const int row = wr * 128 + m * 16 + (lane & 15);
    offA[m] = swz(row * 64 + s16);
  }
#pragma unroll
  for (int n = 0; n < 4; ++n) {
    const int row = wc * 64 + n * 16 + (lane & 15);
    offB[n] = 16384 + swz(row * 64 + s16);
  }

  f32x4 acc[8][4] = {};

  auto STAGE = [&](int q) {
    unsigned char* sb = lds + (q & 3) * 32768;
    const size_t kb = (size_t)q * 64;
    load_lds16(pA0 + kb, sb + physA0);
    load_lds16(pA1 + kb, sb + physA1);
    load_lds16(pB0 + kb, sb + physB0);
    load_lds16(pB1 + kb, sb + physB1);
  };

  // prologue: 3 slots in flight (12 loads); vmcnt(8) retires slot 0's 4
  STAGE(0); STAGE(1); STAGE(2);
  asm volatile("s_waitcnt vmcnt(8)" ::: "memory");
  __builtin_amdgcn_s_barrier();
  __builtin_amdgcn_sched_barrier(0);

  for (int p = 0; p < NPH; ++p) {
    if (p + 3 < NPH) STAGE(p + 3);

    const unsigned char* sl = lds + (p & 3) * 32768;
    bf16x8 af[8], bf[4];
#pragma unroll
    for (int n = 0; n < 4; ++n) bf[n] = *reinterpret_cast<const bf16x8*>(sl + offB[n]);
#pragma unroll
    for (int m = 0; m < 8; ++m) af[m] = *reinterpret_cast<const bf16x8*>(sl + offA[m]);

    __builtin_amdgcn_s_setprio(1);
#pragma unroll
    for (int m = 0; m < 8; ++m)
#pragma unroll
      for (int n = 0; n < 4; ++n)
        acc[m][n] = __builtin_amdgcn_mfma_f32_16x16x32_bf16(af[m], bf[n], acc[m][n], 0, 0, 0);
    __builtin_amdgcn_s_setprio(0);

    if (p < NPH - 1) {
      if (p < NPH - 3)
        asm volatile("s_waitcnt vmcnt(8)" ::: "memory");
      else if (p == NPH - 3)
        asm volatile("s_waitcnt vmcnt(4)" ::: "memory");
      else
        asm volatile("s_waitcnt vmcnt(0)" ::: "memory");
      __builtin_amdgcn_s_barrier();
      __builtin_amdgcn_sched_barrier(0);
    }
  }

  // ---- epilogue: stage bf16 proj tile into LDS, padded row stride 264 elems
  __syncthreads();
  unsigned short* cs = (unsigned short*)lds;
  {
    const int c0 = wc * 64 + (lane & 15);
    const int r00 = wr * 128 + ((lane >> 4) << 2);
#pragma unroll
    for (int m = 0; m < 8; ++m)
#pragma unroll
      for (int n = 0; n < 4; ++n) {
        const int rr = r00 + m * 16;
        const int cc = c0 + n * 16;
#pragma unroll
        for (int r = 0; r < 4; ++r) cs[(rr + r) * 264 + cc] = f2b(acc[m][n][r]);
      }
  }
  __syncthreads();

  // ---- fused gates: 256 rows x 64 h per block
  const int hbase = bcol >> 2;
#pragma unroll 4
  for (int j = 0; j < 32; ++j) {
    const int q = tid + (j << 9);  // 0..16383
    const int row = q >> 6;
    const int hh = q & 63;
    const ushort4 pv = *reinterpret_cast<const ushort4*>(&cs[row * 264 + hh * 4]);
    const int ci = (brow + row) * 1024 + hbase + hh;
    float sf, si, so, sg;
    if constexpr (MODE == 0) {
      const float4 bpv = *reinterpret_cast<const float4*>(&bp[bcol + hh * 4]);
      sf = b2f(pv.x) + bpv.x;
      si = b2f(pv.y) + bpv.y;
      so = b2f(pv.z) + bpv.z;
      sg = b2f(pv.w) + bpv.w;
      ushort4 xo;
      xo.x = f2b(sf); xo.y = f2b(si); xo.z = f2b(so); xo.w = f2b(sg);
      *reinterpret_cast<ushort4*>(&xpb_w[(size_t)(brow + row) * N + bcol + hh * 4]) = xo;
    } else {
      const ushort4 xv = *reinterpret_cast<const ushort4*>(&xpb_r[(size_t)(brow + row) * N + bcol + hh * 4]);
      sf = b2f(pv.x) + b2f(xv.x);
      si = b2f(pv.y) + b2f(xv.y);
      so = b2f(pv.z) + b2f(xv.z);
      sg = b2f(pv.w) + b2f(xv.w);
    }
    const float c_old = (MODE == 0) ? 0.0f : b2f(ct[ci]);
    const float f = sigm(sf);
    const float ii = sigm(si);
    const float o = sigm(so);
    const float gg = tanh_fast(sg);
    const float c = fmaf(f, c_old, ii * gg);
    const float h = o * tanh_fast(c);
    if constexpr (MODE == 2) {
      out[ci] = h;
      out[4194304 + ci] = c;
    } else {
      ct[ci] = f2b(c);
      htout[ci] = f2b(h);
    }
  }
}

// ---------------------------------------------------------------- launch
extern "C" void kernel_launch(void* const* d_in, const int* in_sizes, int n_in,
                              void* d_out, int out_size, void* d_ws, size_t ws_size,
                              hipStream_t stream) {
  const float* x = (const float*)d_in[0];   // [4096,1024]
  const float* W = (const float*)d_in[1];   // [4096,1024]
  const float* bW = (const float*)d_in[2];  // [4096]
  const float* U = (const float*)d_in[3];   // [4096,1024]
  const float* bU = (const float*)d_in[4];  // [4096]
  float* out = (float*)d_out;

  char* w = (char*)d_ws;
  const size_t MB = 1ull << 20;
  unsigned short* xb = (unsigned short*)(w + 0 * MB);    // 8 MB
  unsigned short* Wbp = (unsigned short*)(w + 8 * MB);   // 8 MB (gate-interleaved)
  unsigned short* Ubp = (unsigned short*)(w + 16 * MB);  // 8 MB (gate-interleaved)
  unsigned short* xpb = (unsigned short*)(w + 24 * MB);  // 32 MB [B,4H] bf16 proj+bias
  unsigned short* ct = (unsigned short*)(w + 56 * MB);   // 8 MB bf16 state
  unsigned short* htA = (unsigned short*)(w + 64 * MB);  // 8 MB
  unsigned short* htB = (unsigned short*)(w + 72 * MB);  // 8 MB
  float* bp = (float*)(w + 80 * MB);                     // 16 KB

  const int n4 = (4096 * 1024) / 4;
  cast_kernel<<<4096, 256, 0, stream>>>(x, xb, n4);
  cast_perm_kernel<<<4096, 256, 0, stream>>>(W, Wbp);
  cast_perm_kernel<<<4096, 256, 0, stream>>>(U, Ubp);
  bias_prep<<<16, 256, 0, stream>>>(bW, bU, bp);

  // step 0: x-projection GEMM with fused gates (c0 = 0), writes xpb + ct + htA
  gemm256<0><<<256, 512, 0, stream>>>(xb, Wbp, nullptr, xpb, bp, ct, htA, nullptr);

  const unsigned short* hin = htA;
  unsigned short* hout = htB;
  for (int t = 1; t <= 6; ++t) {
    gemm256<1><<<256, 512, 0, stream>>>(hin, Ubp, xpb, nullptr, nullptr, ct, hout, nullptr);
    const unsigned short* tmp = hout;
    hout = (unsigned short*)hin;
    hin = tmp;
  }
  gemm256<2><<<256, 512, 0, stream>>>(hin, Ubp, xpb, nullptr, nullptr, ct, nullptr, out);
}